// Round 1
// baseline (563.768 us; speedup 1.0000x reference)
//
#include <hip/hip_runtime.h>

// RNNNet: 7-layer tanh RNN, N=65536, T=28, V=28, H=64, 10-class head.
// Fully fused: x -> 7 RNN layers -> classifier, no HBM intermediates.
// Layout: 512 thr (8 waves) / block, each wave privately owns 16 sequences.
// Per-wave LDS slab [7 t][16 s][64 k] bf16, updated in place (layer-outer,
// time-chunked Tc=7, 4 chunks; chunk carry in registers).
// GEMMs via mfma_f32_16x16x32_bf16 with swapped operands: D[j][s] = W x h^T.

namespace {

typedef __attribute__((ext_vector_type(8))) short bf16x8;
typedef __attribute__((ext_vector_type(4))) float f32x4;

constexpr int SLAB_W    = 14336;            // per-wave slab: 7*16*64*2B
constexpr int SCR       = 8 * SLAB_W;       // 114688: carry scratch rows, 8*2048
constexpr int WST       = SCR + 8 * 2048;   // 131072: staged Wih/Whh, 2*8192
constexpr int W0L       = WST + 16384;      // 147456: Wih0 padded [64][64] bf16
constexpr int WCL       = W0L + 8192;       // 155648: Wc padded [16][64] bf16
constexpr int BIA       = WCL + 2048;       // 157696: bih+bhh f32 [7][64]
constexpr int BCV       = BIA + 1792;       // 159488: bc f32 padded [16]
constexpr int LDS_TOTAL = BCV + 64;         // 159552 <= 163840

__device__ __forceinline__ unsigned f2bf(float f) {
    unsigned u = __builtin_bit_cast(unsigned, f);
    return (u + 0x7FFFu + ((u >> 16) & 1u)) >> 16;   // RNE, inputs finite
}
__device__ __forceinline__ unsigned pack2(float a, float b) {
    return f2bf(a) | (f2bf(b) << 16);
}
__device__ __forceinline__ int4 pack8(const float* v) {
    return make_int4((int)pack2(v[0], v[1]), (int)pack2(v[2], v[3]),
                     (int)pack2(v[4], v[5]), (int)pack2(v[6], v[7]));
}
__device__ __forceinline__ float tanh_fast(float v) {
    v = fminf(v, 20.f);                                  // avoid inf/inf
    float z = exp2f(v * 2.8853900817779268f);            // e^(2v)
    return (z - 1.f) * __builtin_amdgcn_rcpf(z + 1.f);
}

} // namespace

__global__ void __launch_bounds__(512, 2)
rnn_fused(const float* __restrict__ x,    const float* __restrict__ Wih0,
          const float* __restrict__ Wih,  const float* __restrict__ Whh,
          const float* __restrict__ bih,  const float* __restrict__ bhh,
          const float* __restrict__ Wc,   const float* __restrict__ bc,
          float* __restrict__ out)
{
    extern __shared__ char smem[];
    const int tid  = threadIdx.x;
    const int lane = tid & 63;
    const int wid  = tid >> 6;          // wave 0..7
    const int sl   = lane & 15;         // s within wave / frag row
    const int g    = lane >> 4;         // lane group 0..3
    const int swzS = (sl & 7) << 4;     // LDS row XOR swizzle
    const int slab0 = wid * SLAB_W;
    const int scr0  = SCR + wid * 2048;
    const int seqbase = blockIdx.x * 128 + wid * 16;

    // ---------------- one-time resident staging ----------------
    {   // Wih0 zero-padded to [64][64] bf16, row-swizzled
        int j = tid >> 3, k0 = (tid & 7) * 8;
        float v[8];
#pragma unroll
        for (int e = 0; e < 8; ++e) v[e] = (k0 + e < 28) ? Wih0[j * 28 + k0 + e] : 0.f;
        *(int4*)(smem + W0L + j * 128 + ((k0 * 2) ^ ((j & 7) << 4))) = pack8(v);
    }
    if (tid < 128) { // Wc zero-padded to [16][64]
        int c = tid >> 3, k0 = (tid & 7) * 8;
        float v[8];
#pragma unroll
        for (int e = 0; e < 8; ++e) v[e] = (c < 10) ? Wc[c * 64 + k0 + e] : 0.f;
        *(int4*)(smem + WCL + c * 128 + ((k0 * 2) ^ ((c & 7) << 4))) = pack8(v);
    }
    if (tid < 448) *(float*)(smem + BIA + tid * 4) = bih[tid] + bhh[tid];
    if (tid < 16)  *(float*)(smem + BCV + tid * 4) = (tid < 10) ? bc[tid] : 0.f;
    __syncthreads();

    unsigned carry[7][8] = {};   // per-layer h(t=chunk_end): 4 jt * 4 bf16 packed

#pragma unroll 1
    for (int chunk = 0; chunk < 4; ++chunk) {
        const int t0 = chunk * 7;

        // ---- stage x into this wave's slab (bf16, swizzled, k>=28 zeroed) ----
#pragma unroll
        for (int it = 0; it < 2; ++it) {
            const int t = g + it * 4;
            if (t < 7) {
                const float* xs = x + (size_t)(seqbase + sl) * 784 + (size_t)(t0 + t) * 28;
                float f[28];
#pragma unroll
                for (int q = 0; q < 7; ++q) {
                    float4 v4 = *(const float4*)(xs + q * 4);
                    f[q * 4 + 0] = v4.x; f[q * 4 + 1] = v4.y;
                    f[q * 4 + 2] = v4.z; f[q * 4 + 3] = v4.w;
                }
                const int rb = slab0 + t * 2048 + sl * 128;
#pragma unroll
                for (int q = 0; q < 7; ++q)
                    *(int2*)(smem + rb + ((q * 8) ^ swzS)) =
                        make_int2((int)pack2(f[q * 4], f[q * 4 + 1]),
                                  (int)pack2(f[q * 4 + 2], f[q * 4 + 3]));
#pragma unroll
                for (int q = 7; q < 16; ++q)   // zero k=28..63 (kill stale NaNs)
                    *(int2*)(smem + rb + ((q * 8) ^ swzS)) = make_int2(0, 0);
            }
        }

#pragma unroll
        for (int l = 0; l < 7; ++l) {
            // ---- stage this layer's weights to LDS (shared, 2 barriers) ----
            __syncthreads();
            {
                int j = tid >> 3, k0 = (tid & 7) * 8;
                if (l >= 1) {
                    const float* src = Wih + (size_t)(l - 1) * 4096 + j * 64 + k0;
                    float4 a4 = *(const float4*)(src);
                    float4 b4 = *(const float4*)(src + 4);
                    float v[8] = {a4.x, a4.y, a4.z, a4.w, b4.x, b4.y, b4.z, b4.w};
                    *(int4*)(smem + WST + j * 128 + ((k0 * 2) ^ ((j & 7) << 4))) = pack8(v);
                }
                const float* srh = Whh + (size_t)l * 4096 + j * 64 + k0;
                float4 a4 = *(const float4*)(srh);
                float4 b4 = *(const float4*)(srh + 4);
                float v[8] = {a4.x, a4.y, a4.z, a4.w, b4.x, b4.y, b4.z, b4.w};
                *(int4*)(smem + WST + 8192 + j * 128 + ((k0 * 2) ^ ((j & 7) << 4))) = pack8(v);
            }
            __syncthreads();

            // ---- hoist W fragments (A-operand: lane&15 = row j) + bias ----
            bf16x8 wihf[4][2], whhf[4][2];
            f32x4  biasr[4];
#pragma unroll
            for (int jt = 0; jt < 4; ++jt) {
                const int rowoff = (jt * 16 + sl) * 128;   // (j&7)==(sl&7)
#pragma unroll
                for (int kf = 0; kf < 2; ++kf) {
                    const int kb = (kf * 64 + g * 16) ^ swzS;
                    wihf[jt][kf] = (l == 0)
                        ? *(const bf16x8*)(smem + W0L + rowoff + kb)
                        : *(const bf16x8*)(smem + WST + rowoff + kb);
                    whhf[jt][kf] = *(const bf16x8*)(smem + WST + 8192 + rowoff + kb);
                }
                biasr[jt] = *(const f32x4*)(smem + BIA + l * 256 + jt * 64 + g * 16);
            }

            // ---- restore carry (h at t0-1) into scratch row ----
#pragma unroll
            for (int jt = 0; jt < 4; ++jt)
                *(int2*)(smem + scr0 + sl * 128 + ((jt * 32 + g * 8) ^ swzS)) =
                    make_int2((int)carry[l][jt * 2], (int)carry[l][jt * 2 + 1]);

            // ---- time loop: in-place slab update, wave-private, no barriers ----
#pragma unroll 1
            for (int tt = 0; tt < 7; ++tt) {
                const int in_base  = slab0 + tt * 2048 + sl * 128;
                const int rec_base = (tt == 0) ? (scr0 + sl * 128)
                                               : (slab0 + (tt - 1) * 2048 + sl * 128);
                // B-operand frags: lane&15 = col s, 8 contiguous k per lane
                bf16x8 bin0 = *(const bf16x8*)(smem + in_base  + (( 0 + g * 16) ^ swzS));
                bf16x8 bin1 = *(const bf16x8*)(smem + in_base  + ((64 + g * 16) ^ swzS));
                bf16x8 br0  = *(const bf16x8*)(smem + rec_base + (( 0 + g * 16) ^ swzS));
                bf16x8 br1  = *(const bf16x8*)(smem + rec_base + ((64 + g * 16) ^ swzS));
#pragma unroll
                for (int jt = 0; jt < 4; ++jt) {
                    f32x4 a = biasr[jt];   // bias as mfma C-in
                    a = __builtin_amdgcn_mfma_f32_16x16x32_bf16(wihf[jt][0], bin0, a, 0, 0, 0);
                    a = __builtin_amdgcn_mfma_f32_16x16x32_bf16(wihf[jt][1], bin1, a, 0, 0, 0);
                    a = __builtin_amdgcn_mfma_f32_16x16x32_bf16(whhf[jt][0], br0, a, 0, 0, 0);
                    a = __builtin_amdgcn_mfma_f32_16x16x32_bf16(whhf[jt][1], br1, a, 0, 0, 0);
                    // D: col = lane&15 = s, rows j = jt*16 + g*4 + r  -> contiguous j
                    unsigned p0 = pack2(tanh_fast(a[0]), tanh_fast(a[1]));
                    unsigned p1 = pack2(tanh_fast(a[2]), tanh_fast(a[3]));
                    if (tt == 6) { carry[l][jt * 2] = p0; carry[l][jt * 2 + 1] = p1; }
                    *(int2*)(smem + in_base + ((jt * 32 + g * 8) ^ swzS)) =
                        make_int2((int)p0, (int)p1);
                }
            }
        }
    }

    // ---------------- classifier: out = h6(t=27) @ Wc^T + bc ----------------
    {
        const int in_base = slab0 + 6 * 2048 + sl * 128;   // last chunk, tt=6 -> t=27
        bf16x8 b0 = *(const bf16x8*)(smem + in_base + (( 0 + g * 16) ^ swzS));
        bf16x8 b1 = *(const bf16x8*)(smem + in_base + ((64 + g * 16) ^ swzS));
        const int rowoff = sl * 128;                        // A row = class c = sl
        bf16x8 w0 = *(const bf16x8*)(smem + WCL + rowoff + (( 0 + g * 16) ^ swzS));
        bf16x8 w1 = *(const bf16x8*)(smem + WCL + rowoff + ((64 + g * 16) ^ swzS));
        f32x4 o = {0.f, 0.f, 0.f, 0.f};
        o = __builtin_amdgcn_mfma_f32_16x16x32_bf16(w0, b0, o, 0, 0, 0);
        o = __builtin_amdgcn_mfma_f32_16x16x32_bf16(w1, b1, o, 0, 0, 0);
        f32x4 bb = *(const f32x4*)(smem + BCV + g * 16);
#pragma unroll
        for (int r = 0; r < 4; ++r) {
            const int c = g * 4 + r;
            if (c < 10)
                out[(size_t)(seqbase + sl) * 10 + c] = o[r] + bb[r];
        }
    }
}

extern "C" void kernel_launch(void* const* d_in, const int* in_sizes, int n_in,
                              void* d_out, int out_size, void* d_ws, size_t ws_size,
                              hipStream_t stream) {
    (void)in_sizes; (void)n_in; (void)d_ws; (void)ws_size; (void)out_size;
    hipFuncSetAttribute((const void*)rnn_fused,
                        hipFuncAttributeMaxDynamicSharedMemorySize, LDS_TOTAL);
    rnn_fused<<<dim3(512), dim3(512), LDS_TOTAL, stream>>>(
        (const float*)d_in[0], (const float*)d_in[1], (const float*)d_in[2],
        (const float*)d_in[3], (const float*)d_in[4], (const float*)d_in[5],
        (const float*)d_in[6], (const float*)d_in[7], (float*)d_out);
}

// Round 2
// 336.347 us; speedup vs baseline: 1.6761x; 1.6761x over previous
//
#include <hip/hip_runtime.h>

// RNNNet: 7-layer tanh RNN, N=65536, T=28, V=28, H=64, 10-class head.
// Fully fused: x -> 7 RNN layers -> classifier, no HBM intermediates.
// 512 thr (8 waves) / block, each wave privately owns 16 sequences.
// Per-wave LDS slab [7 t][16 s][64 k] bf16, in-place update (layer-outer,
// time-chunked Tc=7, 4 chunks; chunk carry in registers).
// GEMMs via mfma_f32_16x16x32_bf16, swapped operands: D[j][s] = W x h^T.
// R2: weights/biases pre-scaled by 2/ln2 so tanh = 1-2*rcp(exp2(a)+1)
//     (4 VALU/elem); bf16 pack via v_cvt_pk_bf16_f32; launch_bounds(512,1)
//     to lift the 128-VGPR cap that caused scratch spills (WRITE_SIZE 38MB).

namespace {

typedef __attribute__((ext_vector_type(8))) short bf16x8;
typedef __attribute__((ext_vector_type(4))) float f32x4;

constexpr int SLAB_W    = 14336;            // per-wave slab: 7*16*64*2B
constexpr int SCR       = 8 * SLAB_W;       // 114688: carry scratch rows, 8*2048
constexpr int WST       = SCR + 8 * 2048;   // 131072: staged Wih/Whh, 2*8192
constexpr int W0L       = WST + 16384;      // 147456: Wih0 padded [64][64] bf16
constexpr int WCL       = W0L + 8192;       // 155648: Wc padded [16][64] bf16
constexpr int BIA       = WCL + 2048;       // 157696: (bih+bhh)*K f32 [7][64]
constexpr int BCV       = BIA + 1792;       // 159488: bc f32 padded [16]
constexpr int LDS_TOTAL = BCV + 64;         // 159552 <= 163840

constexpr float TANH_K = 2.8853900817779268f;   // 2/ln(2)

__device__ __forceinline__ unsigned cvt_pk(float a, float b) {
    unsigned r;                              // r.lo=bf16(a), r.hi=bf16(b), RNE
    asm("v_cvt_pk_bf16_f32 %0, %1, %2" : "=v"(r) : "v"(a), "v"(b));
    return r;
}
__device__ __forceinline__ int4 pack8s(const float* v, float s) {
    return make_int4((int)cvt_pk(v[0] * s, v[1] * s), (int)cvt_pk(v[2] * s, v[3] * s),
                     (int)cvt_pk(v[4] * s, v[5] * s), (int)cvt_pk(v[6] * s, v[7] * s));
}
// input pre-scaled by 2/ln2: tanh = 1 - 2/(2^a + 1). Saturates correctly at
// +/-inf of exp2 (no clamp needed); exp2/rcp are ~1ulp HW ops.
__device__ __forceinline__ float tanh_pre(float a) {
    float z = __builtin_amdgcn_exp2f(a);
    return fmaf(-2.f, __builtin_amdgcn_rcpf(z + 1.f), 1.f);
}

} // namespace

__global__ void __launch_bounds__(512, 1)
rnn_fused(const float* __restrict__ x,    const float* __restrict__ Wih0,
          const float* __restrict__ Wih,  const float* __restrict__ Whh,
          const float* __restrict__ bih,  const float* __restrict__ bhh,
          const float* __restrict__ Wc,   const float* __restrict__ bc,
          float* __restrict__ out)
{
    extern __shared__ char smem[];
    const int tid  = threadIdx.x;
    const int lane = tid & 63;
    const int wid  = tid >> 6;          // wave 0..7
    const int sl   = lane & 15;         // s within wave / frag row
    const int g    = lane >> 4;         // lane group 0..3
    const int swzS = (sl & 7) << 4;     // LDS row XOR swizzle
    const int slab0 = wid * SLAB_W;
    const int scr0  = SCR + wid * 2048;
    const int seqbase = blockIdx.x * 128 + wid * 16;

    // loop-invariant swizzled offsets (keep inner loop to pure adds)
    const int rd0 = (g * 16) ^ swzS;
    const int rd1 = (64 + g * 16) ^ swzS;
    int wro[4];
#pragma unroll
    for (int jt = 0; jt < 4; ++jt) wro[jt] = (jt * 32 + g * 8) ^ swzS;

    // ---------------- one-time resident staging ----------------
    {   // Wih0 zero-padded to [64][64] bf16, row-swizzled, scaled by 2/ln2
        int j = tid >> 3, k0 = (tid & 7) * 8;
        float v[8];
#pragma unroll
        for (int e = 0; e < 8; ++e) v[e] = (k0 + e < 28) ? Wih0[j * 28 + k0 + e] : 0.f;
        *(int4*)(smem + W0L + j * 128 + ((k0 * 2) ^ ((j & 7) << 4))) = pack8s(v, TANH_K);
    }
    if (tid < 128) { // Wc zero-padded to [16][64] (UNscaled: no tanh after)
        int c = tid >> 3, k0 = (tid & 7) * 8;
        float v[8];
#pragma unroll
        for (int e = 0; e < 8; ++e) v[e] = (c < 10) ? Wc[c * 64 + k0 + e] : 0.f;
        *(int4*)(smem + WCL + c * 128 + ((k0 * 2) ^ ((c & 7) << 4))) = pack8s(v, 1.f);
    }
    if (tid < 448) *(float*)(smem + BIA + tid * 4) = (bih[tid] + bhh[tid]) * TANH_K;
    if (tid < 16)  *(float*)(smem + BCV + tid * 4) = (tid < 10) ? bc[tid] : 0.f;
    __syncthreads();

    unsigned carry[7][8] = {};   // per-layer h(t=chunk_end): 4 jt * 4 bf16 packed

#pragma unroll 1
    for (int chunk = 0; chunk < 4; ++chunk) {
        const int t0 = chunk * 7;

        // ---- stage x into this wave's slab (bf16, swizzled, k>=28 zeroed) ----
#pragma unroll
        for (int it = 0; it < 2; ++it) {
            const int t = g + it * 4;
            if (t < 7) {
                const float* xs = x + (size_t)(seqbase + sl) * 784 + (size_t)(t0 + t) * 28;
                float f[28];
#pragma unroll
                for (int q = 0; q < 7; ++q) {
                    float4 v4 = *(const float4*)(xs + q * 4);
                    f[q * 4 + 0] = v4.x; f[q * 4 + 1] = v4.y;
                    f[q * 4 + 2] = v4.z; f[q * 4 + 3] = v4.w;
                }
                const int rb = slab0 + t * 2048 + sl * 128;
#pragma unroll
                for (int q = 0; q < 7; ++q)
                    *(int2*)(smem + rb + ((q * 8) ^ swzS)) =
                        make_int2((int)cvt_pk(f[q * 4], f[q * 4 + 1]),
                                  (int)cvt_pk(f[q * 4 + 2], f[q * 4 + 3]));
#pragma unroll
                for (int q = 7; q < 16; ++q)   // zero k=28..63 (kill stale data)
                    *(int2*)(smem + rb + ((q * 8) ^ swzS)) = make_int2(0, 0);
            }
        }

#pragma unroll
        for (int l = 0; l < 7; ++l) {
            // ---- stage this layer's weights to LDS (scaled by 2/ln2) ----
            __syncthreads();
            {
                int j = tid >> 3, k0 = (tid & 7) * 8;
                if (l >= 1) {
                    const float* src = Wih + (size_t)(l - 1) * 4096 + j * 64 + k0;
                    float4 a4 = *(const float4*)(src);
                    float4 b4 = *(const float4*)(src + 4);
                    float v[8] = {a4.x, a4.y, a4.z, a4.w, b4.x, b4.y, b4.z, b4.w};
                    *(int4*)(smem + WST + j * 128 + ((k0 * 2) ^ ((j & 7) << 4))) = pack8s(v, TANH_K);
                }
                const float* srh = Whh + (size_t)l * 4096 + j * 64 + k0;
                float4 a4 = *(const float4*)(srh);
                float4 b4 = *(const float4*)(srh + 4);
                float v[8] = {a4.x, a4.y, a4.z, a4.w, b4.x, b4.y, b4.z, b4.w};
                *(int4*)(smem + WST + 8192 + j * 128 + ((k0 * 2) ^ ((j & 7) << 4))) = pack8s(v, TANH_K);
            }
            __syncthreads();

            // ---- hoist W fragments (A-operand: lane&15 = row j) + bias ----
            bf16x8 wihf[4][2], whhf[4][2];
            f32x4  biasr[4];
#pragma unroll
            for (int jt = 0; jt < 4; ++jt) {
                const int rowoff = (jt * 16 + sl) * 128;   // (j&7)==(sl&7)
#pragma unroll
                for (int kf = 0; kf < 2; ++kf) {
                    const int kb = (kf * 64 + g * 16) ^ swzS;
                    wihf[jt][kf] = (l == 0)
                        ? *(const bf16x8*)(smem + W0L + rowoff + kb)
                        : *(const bf16x8*)(smem + WST + rowoff + kb);
                    whhf[jt][kf] = *(const bf16x8*)(smem + WST + 8192 + rowoff + kb);
                }
                biasr[jt] = *(const f32x4*)(smem + BIA + l * 256 + jt * 64 + g * 16);
            }

            // ---- restore carry (h at t0-1) into scratch row ----
#pragma unroll
            for (int jt = 0; jt < 4; ++jt)
                *(int2*)(smem + scr0 + sl * 128 + wro[jt]) =
                    make_int2((int)carry[l][jt * 2], (int)carry[l][jt * 2 + 1]);

            // ---- time loop: in-place slab update, wave-private, no barriers ----
#pragma unroll 1
            for (int tt = 0; tt < 7; ++tt) {
                const int in_base  = slab0 + tt * 2048 + sl * 128;
                const int rec_base = (tt == 0) ? (scr0 + sl * 128)
                                               : (slab0 + (tt - 1) * 2048 + sl * 128);
                // B-operand frags: lane&15 = col s, 8 contiguous k per lane
                bf16x8 bin0 = *(const bf16x8*)(smem + in_base  + rd0);
                bf16x8 bin1 = *(const bf16x8*)(smem + in_base  + rd1);
                bf16x8 br0  = *(const bf16x8*)(smem + rec_base + rd0);
                bf16x8 br1  = *(const bf16x8*)(smem + rec_base + rd1);
#pragma unroll
                for (int jt = 0; jt < 4; ++jt) {
                    f32x4 a = biasr[jt];   // bias as mfma C-in
                    a = __builtin_amdgcn_mfma_f32_16x16x32_bf16(wihf[jt][0], bin0, a, 0, 0, 0);
                    a = __builtin_amdgcn_mfma_f32_16x16x32_bf16(wihf[jt][1], bin1, a, 0, 0, 0);
                    a = __builtin_amdgcn_mfma_f32_16x16x32_bf16(whhf[jt][0], br0, a, 0, 0, 0);
                    a = __builtin_amdgcn_mfma_f32_16x16x32_bf16(whhf[jt][1], br1, a, 0, 0, 0);
                    // D: col = lane&15 = s, rows j = jt*16 + g*4 + r
                    unsigned p0 = cvt_pk(tanh_pre(a[0]), tanh_pre(a[1]));
                    unsigned p1 = cvt_pk(tanh_pre(a[2]), tanh_pre(a[3]));
                    if (tt == 6) { carry[l][jt * 2] = p0; carry[l][jt * 2 + 1] = p1; }
                    *(int2*)(smem + in_base + wro[jt]) = make_int2((int)p0, (int)p1);
                }
            }
        }
    }

    // ---------------- classifier: out = h6(t=27) @ Wc^T + bc ----------------
    {
        const int in_base = slab0 + 6 * 2048 + sl * 128;   // last chunk, tt=6 -> t=27
        bf16x8 b0 = *(const bf16x8*)(smem + in_base + rd0);
        bf16x8 b1 = *(const bf16x8*)(smem + in_base + rd1);
        const int rowoff = sl * 128;                        // A row = class c = sl
        bf16x8 w0 = *(const bf16x8*)(smem + WCL + rowoff + rd0);
        bf16x8 w1 = *(const bf16x8*)(smem + WCL + rowoff + rd1);
        f32x4 o = {0.f, 0.f, 0.f, 0.f};
        o = __builtin_amdgcn_mfma_f32_16x16x32_bf16(w0, b0, o, 0, 0, 0);
        o = __builtin_amdgcn_mfma_f32_16x16x32_bf16(w1, b1, o, 0, 0, 0);
        f32x4 bb = *(const f32x4*)(smem + BCV + g * 16);
#pragma unroll
        for (int r = 0; r < 4; ++r) {
            const int c = g * 4 + r;
            if (c < 10)
                out[(size_t)(seqbase + sl) * 10 + c] = o[r] + bb[r];
        }
    }
}

extern "C" void kernel_launch(void* const* d_in, const int* in_sizes, int n_in,
                              void* d_out, int out_size, void* d_ws, size_t ws_size,
                              hipStream_t stream) {
    (void)in_sizes; (void)n_in; (void)d_ws; (void)ws_size; (void)out_size;
    hipFuncSetAttribute((const void*)rnn_fused,
                        hipFuncAttributeMaxDynamicSharedMemorySize, LDS_TOTAL);
    rnn_fused<<<dim3(512), dim3(512), LDS_TOTAL, stream>>>(
        (const float*)d_in[0], (const float*)d_in[1], (const float*)d_in[2],
        (const float*)d_in[3], (const float*)d_in[4], (const float*)d_in[5],
        (const float*)d_in[6], (const float*)d_in[7], (float*)d_out);
}